// Round 3
// baseline (64.706 us; speedup 1.0000x reference)
//
#include <hip/hip_runtime.h>
#include <math.h>

// x: (1,3,48,48,48) fp32, C-contiguous: idx = (cd*48 + h)*48 + w, cd = c*48+d
// out[v] = sum(g*wd*p) / sum(g*wd) -- all normalizations cancel.
// wd*g folded into a single exp2: w = exp2(d^2 * C2 + LG[i]+LG[j]+LG[l])
//   C2   = -1/(2*0.8^2) * log2(e) = -0.78125 * 1.4426950408889634
//   LG[k]= log2(gauss tap k), sigma=1.1: LG = {L0, L1, 0, L1, L0}
// Round 3: 64-thread blocks (1 wave) x 5184 blocks -> ~5 waves/SIMD resident
// (was 432 blocks of 4 waves -> 1-2 waves/SIMD, latency-bound).

__global__ __launch_bounds__(64)
void bilateral3d(const float* __restrict__ x, float* __restrict__ out) {
    constexpr float C2 = -1.1271055f;
    constexpr float L0 = -2.3846116f;
    constexpr float L1 = -0.5961529f;
    constexpr float LG[5] = {L0, L1, 0.0f, L1, L0};

    const int w0 = blockIdx.x * 16 + threadIdx.x;   // 0..47
    const int h0 = blockIdx.y * 4 + threadIdx.y;    // 0..47
    const int cd = blockIdx.z;                      // c*48 + d
    const int d0 = cd % 48;
    const int dz = cd - d0;                         // c*48

    // hoisted clamped offsets (replicate pad)
    int dd[5], hh[5], ww[5];
    #pragma unroll
    for (int k = 0; k < 5; ++k) {
        int a = d0 + k - 2; dd[k] = a < 0 ? 0 : (a > 47 ? 47 : a);
        int b = h0 + k - 2; hh[k] = b < 0 ? 0 : (b > 47 ? 47 : b);
        int c = w0 + k - 2; ww[k] = c < 0 ? 0 : (c > 47 ? 47 : c);
    }

    // 25 precomputed row bases
    int rb[25];
    #pragma unroll
    for (int i = 0; i < 5; ++i)
        #pragma unroll
        for (int j = 0; j < 5; ++j)
            rb[i * 5 + j] = (dz + dd[i]) * 2304 + hh[j] * 48;

    const int center_idx = (cd * 48 + h0) * 48 + w0;
    const float center = x[center_idx];

    float num = 0.0f, den = 0.0f;

    #pragma unroll
    for (int i = 0; i < 5; ++i) {
        #pragma unroll
        for (int j = 0; j < 5; ++j) {
            const int base = rb[i * 5 + j];
            const float Lij = LG[i] + LG[j];        // compile-time constant
            #pragma unroll
            for (int l = 0; l < 5; ++l) {
                const float p = x[base + ww[l]];
                const float dlt = p - center;
                const float t = dlt * dlt;
                const float e = __builtin_amdgcn_exp2f(fmaf(t, C2, Lij + LG[l]));
                num = fmaf(e, p, num);
                den += e;
            }
        }
    }

    out[center_idx] = num / den;
}

extern "C" void kernel_launch(void* const* d_in, const int* in_sizes, int n_in,
                              void* d_out, int out_size, void* d_ws, size_t ws_size,
                              hipStream_t stream) {
    const float* x = (const float*)d_in[0];
    float* out = (float*)d_out;

    dim3 block(16, 4, 1);
    dim3 grid(3, 12, 3 * 48);   // w-tiles, h-tiles, c*d slices
    hipLaunchKernelGGL(bilateral3d, grid, block, 0, stream, x, out);
}